// Round 1
// baseline (2640.776 us; speedup 1.0000x reference)
//
#include <hip/hip_runtime.h>

#define NU 100000
#define NI 100000
#define NE 1600000
#define BB 16384
#define DD 128

static constexpr int SCAN_CHUNK = 2048;                       // 256 threads * 8
static constexpr int SCAN_NBLK  = (NU + SCAN_CHUNK - 1) / SCAN_CHUNK; // 49

// ---------- workspace layout (bytes) ----------
static constexpr size_t OFF_DEG      = 0;          // int[NU]   400000
static constexpr size_t OFF_ROWSTART = 400128;     // int[NU]
static constexpr size_t OFF_CURSOR   = 800256;     // int[NU]
static constexpr size_t OFF_BSUM     = 1200384;    // int[64]
static constexpr size_t OFF_EDGESRC  = 1200640;    // int[NE]   6400000
static constexpr size_t OFF_H1       = 7600640;    // float[NU*DD] 51200000
// end = 58,800,640 bytes

// ---------- helpers ----------
__device__ __forceinline__ unsigned pack_bf16_pair(float a, float b) {
    unsigned ua = __float_as_uint(a);
    unsigned ub = __float_as_uint(b);
    ua = ((ua + 0x7fffu + ((ua >> 16) & 1u)) >> 16) & 0xffffu;  // RNE
    ub = ((ub + 0x7fffu + ((ub >> 16) & 1u)) >> 16) & 0xffffu;
    return ua | (ub << 16);
}

__device__ __forceinline__ float2 unpack_bf16_pair(unsigned u) {
    float2 r;
    r.x = __uint_as_float(u << 16);
    r.y = __uint_as_float(u & 0xffff0000u);
    return r;
}

__device__ __forceinline__ float bcastf(float v, int srcLane) {
    return __uint_as_float(__builtin_amdgcn_readlane(__float_as_uint(v), srcLane));
}

__device__ __forceinline__ float wave_sum(float v) {
    #pragma unroll
    for (int off = 32; off > 0; off >>= 1) v += __shfl_xor(v, off, 64);
    return v;
}

// leaky_relu(0.2) on the lane's two columns, then row-wide l2 normalize.
__device__ __forceinline__ float2 leaky_l2(float x0, float x1) {
    x0 = (x0 > 0.f) ? x0 : 0.2f * x0;
    x1 = (x1 > 0.f) ? x1 : 0.2f * x1;
    float ss = wave_sum(x0 * x0 + x1 * x1);
    float scale = 1.0f / fmaxf(sqrtf(ss), 1e-12f);
    return make_float2(x0 * scale, x1 * scale);
}

// K=128 matmul partial: acc[cols 2*lane, 2*lane+1] += a_row @ W (W packed bf16 in LDS).
// a[r] holds the row distributed: lane l owns elements (2l, 2l+1). NR rows at once.
template <int NR>
__device__ __forceinline__ void mat128_acc(const unsigned* __restrict__ wbase, int lane,
                                           const float2* a, float* acc0, float* acc1) {
    #pragma unroll
    for (int kk = 0; kk < 64; ++kk) {
        float2 w0 = unpack_bf16_pair(wbase[(2 * kk) * 64 + lane]);      // W[2kk][2l..2l+1]
        float2 w1 = unpack_bf16_pair(wbase[(2 * kk + 1) * 64 + lane]);  // W[2kk+1][..]
        #pragma unroll
        for (int r = 0; r < NR; ++r) {
            float hx = bcastf(a[r].x, kk);  // h[2kk]
            float hy = bcastf(a[r].y, kk);  // h[2kk+1]
            acc0[r] += hx * w0.x + hy * w1.x;
            acc1[r] += hx * w0.y + hy * w1.y;
        }
    }
}

// ---------- CSR build ----------
__global__ __launch_bounds__(256) void deg_count_kernel(const int* __restrict__ dst,
                                                        int* __restrict__ deg) {
    int i = blockIdx.x * blockDim.x + threadIdx.x;
    int stride = gridDim.x * blockDim.x;
    for (; i < NE; i += stride) atomicAdd(&deg[dst[i]], 1);
}

__global__ __launch_bounds__(256) void scan1_kernel(const int* __restrict__ deg,
                                                    int* __restrict__ bsum) {
    __shared__ int sh[256];
    int t = threadIdx.x;
    int base = blockIdx.x * SCAN_CHUNK + t * 8;
    int s = 0;
    #pragma unroll
    for (int j = 0; j < 8; ++j) {
        int idx = base + j;
        s += (idx < NU) ? deg[idx] : 0;
    }
    sh[t] = s;
    __syncthreads();
    for (int off = 128; off > 0; off >>= 1) {
        if (t < off) sh[t] += sh[t + off];
        __syncthreads();
    }
    if (t == 0) bsum[blockIdx.x] = sh[0];
}

__global__ void scan2_kernel(int* __restrict__ bsum) {
    if (threadIdx.x == 0) {
        int acc = 0;
        for (int i = 0; i < SCAN_NBLK; ++i) {
            int v = bsum[i];
            bsum[i] = acc;
            acc += v;
        }
    }
}

__global__ __launch_bounds__(256) void scan3_kernel(const int* __restrict__ deg,
                                                    const int* __restrict__ bsum,
                                                    int* __restrict__ row_start,
                                                    int* __restrict__ cursor) {
    __shared__ int sh[256];
    int t = threadIdx.x;
    int base = blockIdx.x * SCAN_CHUNK + t * 8;
    int v[8];
    int s = 0;
    #pragma unroll
    for (int j = 0; j < 8; ++j) {
        int idx = base + j;
        v[j] = (idx < NU) ? deg[idx] : 0;
        s += v[j];
    }
    sh[t] = s;
    __syncthreads();
    // Hillis-Steele inclusive scan over 256 thread sums
    for (int off = 1; off < 256; off <<= 1) {
        int val = sh[t];
        int add = (t >= off) ? sh[t - off] : 0;
        __syncthreads();
        sh[t] = val + add;
        __syncthreads();
    }
    int excl = sh[t] - s + bsum[blockIdx.x];
    #pragma unroll
    for (int j = 0; j < 8; ++j) {
        int idx = base + j;
        if (idx < NU) {
            row_start[idx] = excl;
            cursor[idx] = excl;
        }
        excl += v[j];
    }
}

__global__ __launch_bounds__(256) void fill_kernel(const int* __restrict__ src,
                                                   const int* __restrict__ dst,
                                                   int* __restrict__ cursor,
                                                   int* __restrict__ edge_src) {
    int i = blockIdx.x * blockDim.x + threadIdx.x;
    int stride = gridDim.x * blockDim.x;
    for (; i < NE; i += stride) {
        int d = dst[i];
        int p = atomicAdd(&cursor[d], 1);
        edge_src[p] = src[i];
    }
}

// ---------- layer-1 aggregation: one wave per dst row, no atomics ----------
__global__ __launch_bounds__(256) void agg_kernel(const float* __restrict__ h,
                                                  const int* __restrict__ row_start,
                                                  const int* __restrict__ deg,
                                                  const int* __restrict__ edge_src,
                                                  float* __restrict__ hn) {
    int wid = blockIdx.x * 4 + (threadIdx.x >> 6);
    int lane = threadIdx.x & 63;
    if (wid >= NU) return;
    int st = row_start[wid];
    int dg = deg[wid];
    int en = st + dg;
    float ax = 0.f, ay = 0.f;
    int e = st;
    for (; e + 4 <= en; e += 4) {  // 4-wide MLP
        int s0 = edge_src[e], s1 = edge_src[e + 1], s2 = edge_src[e + 2], s3 = edge_src[e + 3];
        float2 v0 = ((const float2*)(h + (size_t)s0 * DD))[lane];
        float2 v1 = ((const float2*)(h + (size_t)s1 * DD))[lane];
        float2 v2 = ((const float2*)(h + (size_t)s2 * DD))[lane];
        float2 v3 = ((const float2*)(h + (size_t)s3 * DD))[lane];
        ax += v0.x + v1.x + v2.x + v3.x;
        ay += v0.y + v1.y + v2.y + v3.y;
    }
    for (; e < en; ++e) {
        int s = edge_src[e];
        float2 v = ((const float2*)(h + (size_t)s * DD))[lane];
        ax += v.x;
        ay += v.y;
    }
    float inv = 1.0f / fmaxf((float)dg, 1.0f);
    ((float2*)(hn + (size_t)wid * DD))[lane] = make_float2(ax * inv, ay * inv);
}

// ---------- user layer 1 (all rows): out = l2(leaky(h@Ws + hn@Wn + b)) ----------
__global__ __launch_bounds__(256) void user_mm_kernel(const float* __restrict__ hself,
                                                      const float* __restrict__ hneigh,
                                                      const float* __restrict__ Ws,
                                                      const float* __restrict__ Wn,
                                                      const float* __restrict__ bias,
                                                      float* __restrict__ out) {
    __shared__ unsigned ldsw[256 * 64];  // [Ws;Wn] bf16-pair packed, 64 KB
    int t = threadIdx.x;
    for (int i = t; i < 256 * 64; i += 256) {
        int k = i >> 6, l = i & 63;
        const float* p = (k < 128) ? (Ws + (size_t)k * DD + 2 * l)
                                   : (Wn + (size_t)(k - 128) * DD + 2 * l);
        ldsw[i] = pack_bf16_pair(p[0], p[1]);
    }
    __syncthreads();
    int lane = t & 63, wave = t >> 6;
    int base = blockIdx.x * 128 + wave * 32;  // 32 contiguous rows per wave
    float2 bv = ((const float2*)bias)[lane];
    for (int g = 0; g < 8; ++g) {
        int gbase = base + g * 4;
        if (gbase >= NU) break;  // NU % 4 == 0, groups all-or-nothing
        float2 as[4], an[4];
        #pragma unroll
        for (int r = 0; r < 4; ++r) {
            as[r] = ((const float2*)(hself + (size_t)(gbase + r) * DD))[lane];
            an[r] = ((const float2*)(hneigh + (size_t)(gbase + r) * DD))[lane];
        }
        float acc0[4], acc1[4];
        #pragma unroll
        for (int r = 0; r < 4; ++r) { acc0[r] = bv.x; acc1[r] = bv.y; }
        mat128_acc<4>(ldsw, lane, as, acc0, acc1);
        mat128_acc<4>(ldsw + 128 * 64, lane, an, acc0, acc1);
        #pragma unroll
        for (int r = 0; r < 4; ++r) {
            float2 o = leaky_l2(acc0[r], acc1[r]);
            ((float2*)(out + (size_t)(gbase + r) * DD))[lane] = o;
        }
    }
}

// ---------- user layer 2, only `users` rows, fused agg + mm + output write ----------
__global__ __launch_bounds__(256) void user_l2_kernel(const float* __restrict__ ufeat,
                                                      const float* __restrict__ h1,
                                                      const int* __restrict__ users,
                                                      const int* __restrict__ row_start,
                                                      const int* __restrict__ deg,
                                                      const int* __restrict__ edge_src,
                                                      const float* __restrict__ Ws,
                                                      const float* __restrict__ Wn,
                                                      const float* __restrict__ bias,
                                                      float* __restrict__ out) {
    __shared__ unsigned ldsw[256 * 64];
    int t = threadIdx.x;
    for (int i = t; i < 256 * 64; i += 256) {
        int k = i >> 6, l = i & 63;
        const float* p = (k < 128) ? (Ws + (size_t)k * DD + 2 * l)
                                   : (Wn + (size_t)(k - 128) * DD + 2 * l);
        ldsw[i] = pack_bf16_pair(p[0], p[1]);
    }
    __syncthreads();
    int lane = t & 63, wave = t >> 6;
    int base = blockIdx.x * 64 + wave * 16;  // 16 output rows per wave
    float2 bv = ((const float2*)bias)[lane];
    for (int g = 0; g < 4; ++g) {
        int gb = base + g * 4;
        float2 as[4], an[4];
        int uu[4];
        #pragma unroll
        for (int r = 0; r < 4; ++r) {
            int u = users[gb + r];
            uu[r] = u;
            as[r] = ((const float2*)(h1 + (size_t)u * DD))[lane];
            int st = row_start[u];
            int dg = deg[u];
            int en = st + dg;
            float ax = 0.f, ay = 0.f;
            int e = st;
            for (; e + 4 <= en; e += 4) {
                int s0 = edge_src[e], s1 = edge_src[e + 1];
                int s2 = edge_src[e + 2], s3 = edge_src[e + 3];
                float2 v0 = ((const float2*)(h1 + (size_t)s0 * DD))[lane];
                float2 v1 = ((const float2*)(h1 + (size_t)s1 * DD))[lane];
                float2 v2 = ((const float2*)(h1 + (size_t)s2 * DD))[lane];
                float2 v3 = ((const float2*)(h1 + (size_t)s3 * DD))[lane];
                ax += v0.x + v1.x + v2.x + v3.x;
                ay += v0.y + v1.y + v2.y + v3.y;
            }
            for (; e < en; ++e) {
                int s = edge_src[e];
                float2 v = ((const float2*)(h1 + (size_t)s * DD))[lane];
                ax += v.x;
                ay += v.y;
            }
            float inv = 1.0f / fmaxf((float)dg, 1.0f);
            an[r] = make_float2(ax * inv, ay * inv);
        }
        float acc0[4], acc1[4];
        #pragma unroll
        for (int r = 0; r < 4; ++r) { acc0[r] = bv.x; acc1[r] = bv.y; }
        mat128_acc<4>(ldsw, lane, as, acc0, acc1);
        mat128_acc<4>(ldsw + 128 * 64, lane, an, acc0, acc1);
        #pragma unroll
        for (int r = 0; r < 4; ++r) {
            float2 o = leaky_l2(acc0[r], acc1[r]);
            float* orow = out + (size_t)(gb + r) * 384;
            ((float2*)orow)[lane] = ((const float2*)(ufeat + (size_t)uu[r] * DD))[lane];
            ((float2*)orow)[64 + lane] = as[r];
            ((float2*)orow)[128 + lane] = o;
        }
    }
}

// ---------- item side: only selected rows, 2 layers fused ----------
__global__ __launch_bounds__(256) void item_kernel(const float* __restrict__ ifeat,
                                                   const int* __restrict__ pos,
                                                   const int* __restrict__ neg,
                                                   const float* __restrict__ W0,
                                                   const float* __restrict__ b0,
                                                   const float* __restrict__ W1,
                                                   const float* __restrict__ b1,
                                                   float* __restrict__ out) {
    __shared__ unsigned ldsw[2 * 128 * 64];  // W0 then W1, 64 KB
    int t = threadIdx.x;
    for (int i = t; i < 128 * 64; i += 256) {
        int k = i >> 6, l = i & 63;
        ldsw[i] = pack_bf16_pair(W0[(size_t)k * DD + 2 * l], W0[(size_t)k * DD + 2 * l + 1]);
        ldsw[128 * 64 + i] =
            pack_bf16_pair(W1[(size_t)k * DD + 2 * l], W1[(size_t)k * DD + 2 * l + 1]);
    }
    __syncthreads();
    int lane = t & 63, wave = t >> 6;
    int base = blockIdx.x * 256 + wave * 64;  // 64 rows per wave; 2*BB rows total
    float2 b0v = ((const float2*)b0)[lane];
    float2 b1v = ((const float2*)b1)[lane];
    for (int g = 0; g < 16; ++g) {
        int gb = base + g * 4;
        float2 r0[4];
        #pragma unroll
        for (int r = 0; r < 4; ++r) {
            int b = gb + r;
            int it = (b < BB) ? pos[b] : neg[b - BB];
            r0[r] = ((const float2*)(ifeat + (size_t)it * DD))[lane];
        }
        float acc0[4], acc1[4];
        #pragma unroll
        for (int r = 0; r < 4; ++r) { acc0[r] = b0v.x; acc1[r] = b0v.y; }
        mat128_acc<4>(ldsw, lane, r0, acc0, acc1);
        float2 r1[4];
        #pragma unroll
        for (int r = 0; r < 4; ++r) r1[r] = leaky_l2(acc0[r], acc1[r]);
        #pragma unroll
        for (int r = 0; r < 4; ++r) { acc0[r] = b1v.x; acc1[r] = b1v.y; }
        mat128_acc<4>(ldsw + 128 * 64, lane, r1, acc0, acc1);
        #pragma unroll
        for (int r = 0; r < 4; ++r) {
            float2 r2 = leaky_l2(acc0[r], acc1[r]);
            int b = gb + r;
            size_t obase = (b < BB) ? ((size_t)BB * 384 + (size_t)b * 384)
                                    : ((size_t)2 * BB * 384 + (size_t)(b - BB) * 384);
            float* orow = out + obase;
            ((float2*)orow)[lane] = r0[r];
            ((float2*)orow)[64 + lane] = r1[r];
            ((float2*)orow)[128 + lane] = r2;
        }
    }
}

extern "C" void kernel_launch(void* const* d_in, const int* in_sizes, int n_in,
                              void* d_out, int out_size, void* d_ws, size_t ws_size,
                              hipStream_t stream) {
    const int* src = (const int*)d_in[0];
    const int* dst = (const int*)d_in[1];
    const int* users = (const int*)d_in[2];
    const int* pos = (const int*)d_in[3];
    const int* neg = (const int*)d_in[4];
    const float* ufeat = (const float*)d_in[5];
    const float* ifeat = (const float*)d_in[6];
    const float* Ws0 = (const float*)d_in[7];
    const float* Wn0 = (const float*)d_in[8];
    const float* bu0 = (const float*)d_in[9];
    const float* Wi0 = (const float*)d_in[10];
    const float* bi0 = (const float*)d_in[11];
    const float* Ws1 = (const float*)d_in[12];
    const float* Wn1 = (const float*)d_in[13];
    const float* bu1 = (const float*)d_in[14];
    const float* Wi1 = (const float*)d_in[15];
    const float* bi1 = (const float*)d_in[16];
    float* out = (float*)d_out;

    char* ws = (char*)d_ws;
    int* deg = (int*)(ws + OFF_DEG);
    int* row_start = (int*)(ws + OFF_ROWSTART);
    int* cursor = (int*)(ws + OFF_CURSOR);
    int* bsum = (int*)(ws + OFF_BSUM);
    int* edge_src = (int*)(ws + OFF_EDGESRC);
    float* h1 = (float*)(ws + OFF_H1);
    // neighbor-mean buffer lives in d_out (51.2 MB <= 75.5 MB); dead before
    // any real output is written (user_l2/item run after user_mm consumed it).
    float* hn = out;

    hipMemsetAsync(deg, 0, NU * sizeof(int), stream);
    deg_count_kernel<<<(NE + 255) / 256, 256, 0, stream>>>(dst, deg);
    scan1_kernel<<<SCAN_NBLK, 256, 0, stream>>>(deg, bsum);
    scan2_kernel<<<1, 64, 0, stream>>>(bsum);
    scan3_kernel<<<SCAN_NBLK, 256, 0, stream>>>(deg, bsum, row_start, cursor);
    fill_kernel<<<(NE + 255) / 256, 256, 0, stream>>>(src, dst, cursor, edge_src);
    agg_kernel<<<(NU + 3) / 4, 256, 0, stream>>>(ufeat, row_start, deg, edge_src, hn);
    user_mm_kernel<<<(NU + 127) / 128, 256, 0, stream>>>(ufeat, hn, Ws0, Wn0, bu0, h1);
    user_l2_kernel<<<BB / 64, 256, 0, stream>>>(ufeat, h1, users, row_start, deg, edge_src,
                                                Ws1, Wn1, bu1, out);
    item_kernel<<<(2 * BB) / 256, 256, 0, stream>>>(ifeat, pos, neg, Wi0, bi0, Wi1, bi1, out);
}

// Round 2
// 936.123 us; speedup vs baseline: 2.8210x; 2.8210x over previous
//
#include <hip/hip_runtime.h>

#define NU 100000
#define NI 100000
#define NE 1600000
#define BB 16384
#define DD 128

static constexpr int SCAN_CHUNK = 2048;                       // 256 threads * 8
static constexpr int SCAN_NBLK  = (NU + SCAN_CHUNK - 1) / SCAN_CHUNK; // 49

// ---------- workspace layout (bytes) ----------
static constexpr size_t OFF_DEG      = 0;          // int[NU]   400000
static constexpr size_t OFF_ROWSTART = 400128;     // int[NU]
static constexpr size_t OFF_CURSOR   = 800256;     // int[NU]
static constexpr size_t OFF_BSUM     = 1200384;    // int[64]
static constexpr size_t OFF_EDGESRC  = 1200640;    // int[NE]   6400000
static constexpr size_t OFF_H1       = 7600640;    // float[NU*DD] 51200000
// end = 58,800,640 bytes

// ---------- helpers ----------
__device__ __forceinline__ unsigned pack_bf16_pair(float a, float b) {
    unsigned ua = __float_as_uint(a);
    unsigned ub = __float_as_uint(b);
    ua = ((ua + 0x7fffu + ((ua >> 16) & 1u)) >> 16) & 0xffffu;  // RNE
    ub = ((ub + 0x7fffu + ((ub >> 16) & 1u)) >> 16) & 0xffffu;
    return ua | (ub << 16);
}

__device__ __forceinline__ float2 unpack_bf16_pair(unsigned u) {
    float2 r;
    r.x = __uint_as_float(u << 16);
    r.y = __uint_as_float(u & 0xffff0000u);
    return r;
}

__device__ __forceinline__ float bcastf(float v, int srcLane) {
    return __uint_as_float(__builtin_amdgcn_readlane(__float_as_uint(v), srcLane));
}

__device__ __forceinline__ float wave_sum(float v) {
    #pragma unroll
    for (int off = 32; off > 0; off >>= 1) v += __shfl_xor(v, off, 64);
    return v;
}

// leaky_relu(0.2) on the lane's two columns, then row-wide l2 normalize.
__device__ __forceinline__ float2 leaky_l2(float x0, float x1) {
    x0 = (x0 > 0.f) ? x0 : 0.2f * x0;
    x1 = (x1 > 0.f) ? x1 : 0.2f * x1;
    float ss = wave_sum(x0 * x0 + x1 * x1);
    float scale = 1.0f / fmaxf(sqrtf(ss), 1e-12f);
    return make_float2(x0 * scale, x1 * scale);
}

// K=128 matmul partial: acc[cols 2*lane, 2*lane+1] += a_row @ W (W packed bf16 in LDS).
// a[r] holds the row distributed: lane l owns elements (2l, 2l+1). NR rows at once.
// NOTE: unroll capped at 4 — full unroll (round 1) spilled to scratch (VGPR=256,
// 515 MB scratch FETCH, 1380 us for item_kernel). kk stays SGPR-uniform so
// v_readlane_b32 takes the lane index from an SGPR.
template <int NR>
__device__ __forceinline__ void mat128_acc(const unsigned* __restrict__ wbase, int lane,
                                           const float2* a, float* acc0, float* acc1) {
    #pragma unroll 4
    for (int kk = 0; kk < 64; ++kk) {
        float2 w0 = unpack_bf16_pair(wbase[(2 * kk) * 64 + lane]);      // W[2kk][2l..2l+1]
        float2 w1 = unpack_bf16_pair(wbase[(2 * kk + 1) * 64 + lane]);  // W[2kk+1][..]
        #pragma unroll
        for (int r = 0; r < NR; ++r) {
            float hx = bcastf(a[r].x, kk);  // h[2kk]
            float hy = bcastf(a[r].y, kk);  // h[2kk+1]
            acc0[r] += hx * w0.x + hy * w1.x;
            acc1[r] += hx * w0.y + hy * w1.y;
        }
    }
}

// ---------- CSR build ----------
__global__ __launch_bounds__(256) void deg_count_kernel(const int* __restrict__ dst,
                                                        int* __restrict__ deg) {
    int i = blockIdx.x * blockDim.x + threadIdx.x;
    int stride = gridDim.x * blockDim.x;
    for (; i < NE; i += stride) atomicAdd(&deg[dst[i]], 1);
}

__global__ __launch_bounds__(256) void scan1_kernel(const int* __restrict__ deg,
                                                    int* __restrict__ bsum) {
    __shared__ int sh[256];
    int t = threadIdx.x;
    int base = blockIdx.x * SCAN_CHUNK + t * 8;
    int s = 0;
    #pragma unroll
    for (int j = 0; j < 8; ++j) {
        int idx = base + j;
        s += (idx < NU) ? deg[idx] : 0;
    }
    sh[t] = s;
    __syncthreads();
    for (int off = 128; off > 0; off >>= 1) {
        if (t < off) sh[t] += sh[t + off];
        __syncthreads();
    }
    if (t == 0) bsum[blockIdx.x] = sh[0];
}

__global__ void scan2_kernel(int* __restrict__ bsum) {
    if (threadIdx.x == 0) {
        int acc = 0;
        for (int i = 0; i < SCAN_NBLK; ++i) {
            int v = bsum[i];
            bsum[i] = acc;
            acc += v;
        }
    }
}

__global__ __launch_bounds__(256) void scan3_kernel(const int* __restrict__ deg,
                                                    const int* __restrict__ bsum,
                                                    int* __restrict__ row_start,
                                                    int* __restrict__ cursor) {
    __shared__ int sh[256];
    int t = threadIdx.x;
    int base = blockIdx.x * SCAN_CHUNK + t * 8;
    int v[8];
    int s = 0;
    #pragma unroll
    for (int j = 0; j < 8; ++j) {
        int idx = base + j;
        v[j] = (idx < NU) ? deg[idx] : 0;
        s += v[j];
    }
    sh[t] = s;
    __syncthreads();
    // Hillis-Steele inclusive scan over 256 thread sums
    for (int off = 1; off < 256; off <<= 1) {
        int val = sh[t];
        int add = (t >= off) ? sh[t - off] : 0;
        __syncthreads();
        sh[t] = val + add;
        __syncthreads();
    }
    int excl = sh[t] - s + bsum[blockIdx.x];
    #pragma unroll
    for (int j = 0; j < 8; ++j) {
        int idx = base + j;
        if (idx < NU) {
            row_start[idx] = excl;
            cursor[idx] = excl;
        }
        excl += v[j];
    }
}

__global__ __launch_bounds__(256) void fill_kernel(const int* __restrict__ src,
                                                   const int* __restrict__ dst,
                                                   int* __restrict__ cursor,
                                                   int* __restrict__ edge_src) {
    int i = blockIdx.x * blockDim.x + threadIdx.x;
    int stride = gridDim.x * blockDim.x;
    for (; i < NE; i += stride) {
        int d = dst[i];
        int p = atomicAdd(&cursor[d], 1);
        edge_src[p] = src[i];
    }
}

// ---------- layer-1 aggregation: one wave per dst row, no atomics ----------
__global__ __launch_bounds__(256) void agg_kernel(const float* __restrict__ h,
                                                  const int* __restrict__ row_start,
                                                  const int* __restrict__ deg,
                                                  const int* __restrict__ edge_src,
                                                  float* __restrict__ hn) {
    int wid = blockIdx.x * 4 + (threadIdx.x >> 6);
    int lane = threadIdx.x & 63;
    if (wid >= NU) return;
    int st = row_start[wid];
    int dg = deg[wid];
    int en = st + dg;
    float ax = 0.f, ay = 0.f;
    int e = st;
    for (; e + 4 <= en; e += 4) {  // 4-wide MLP
        int s0 = edge_src[e], s1 = edge_src[e + 1], s2 = edge_src[e + 2], s3 = edge_src[e + 3];
        float2 v0 = ((const float2*)(h + (size_t)s0 * DD))[lane];
        float2 v1 = ((const float2*)(h + (size_t)s1 * DD))[lane];
        float2 v2 = ((const float2*)(h + (size_t)s2 * DD))[lane];
        float2 v3 = ((const float2*)(h + (size_t)s3 * DD))[lane];
        ax += v0.x + v1.x + v2.x + v3.x;
        ay += v0.y + v1.y + v2.y + v3.y;
    }
    for (; e < en; ++e) {
        int s = edge_src[e];
        float2 v = ((const float2*)(h + (size_t)s * DD))[lane];
        ax += v.x;
        ay += v.y;
    }
    float inv = 1.0f / fmaxf((float)dg, 1.0f);
    ((float2*)(hn + (size_t)wid * DD))[lane] = make_float2(ax * inv, ay * inv);
}

// ---------- user layer 1 (all rows): out = l2(leaky(h@Ws + hn@Wn + b)) ----------
__global__ __launch_bounds__(256) void user_mm_kernel(const float* __restrict__ hself,
                                                      const float* __restrict__ hneigh,
                                                      const float* __restrict__ Ws,
                                                      const float* __restrict__ Wn,
                                                      const float* __restrict__ bias,
                                                      float* __restrict__ out) {
    __shared__ unsigned ldsw[256 * 64];  // [Ws;Wn] bf16-pair packed, 64 KB
    int t = threadIdx.x;
    for (int i = t; i < 256 * 64; i += 256) {
        int k = i >> 6, l = i & 63;
        const float* p = (k < 128) ? (Ws + (size_t)k * DD + 2 * l)
                                   : (Wn + (size_t)(k - 128) * DD + 2 * l);
        ldsw[i] = pack_bf16_pair(p[0], p[1]);
    }
    __syncthreads();
    int lane = t & 63, wave = t >> 6;
    int base = blockIdx.x * 64 + wave * 16;  // 16 contiguous rows per wave
    float2 bv = ((const float2*)bias)[lane];
    for (int g = 0; g < 4; ++g) {
        int gbase = base + g * 4;
        if (gbase >= NU) break;  // NU % 4 == 0, groups all-or-nothing
        float2 as[4], an[4];
        #pragma unroll
        for (int r = 0; r < 4; ++r) {
            as[r] = ((const float2*)(hself + (size_t)(gbase + r) * DD))[lane];
            an[r] = ((const float2*)(hneigh + (size_t)(gbase + r) * DD))[lane];
        }
        float acc0[4], acc1[4];
        #pragma unroll
        for (int r = 0; r < 4; ++r) { acc0[r] = bv.x; acc1[r] = bv.y; }
        mat128_acc<4>(ldsw, lane, as, acc0, acc1);
        mat128_acc<4>(ldsw + 128 * 64, lane, an, acc0, acc1);
        #pragma unroll
        for (int r = 0; r < 4; ++r) {
            float2 o = leaky_l2(acc0[r], acc1[r]);
            ((float2*)(out + (size_t)(gbase + r) * DD))[lane] = o;
        }
    }
}

// ---------- user layer 2, only `users` rows, fused agg + mm + output write ----------
__global__ __launch_bounds__(256) void user_l2_kernel(const float* __restrict__ ufeat,
                                                      const float* __restrict__ h1,
                                                      const int* __restrict__ users,
                                                      const int* __restrict__ row_start,
                                                      const int* __restrict__ deg,
                                                      const int* __restrict__ edge_src,
                                                      const float* __restrict__ Ws,
                                                      const float* __restrict__ Wn,
                                                      const float* __restrict__ bias,
                                                      float* __restrict__ out) {
    __shared__ unsigned ldsw[256 * 64];
    int t = threadIdx.x;
    for (int i = t; i < 256 * 64; i += 256) {
        int k = i >> 6, l = i & 63;
        const float* p = (k < 128) ? (Ws + (size_t)k * DD + 2 * l)
                                   : (Wn + (size_t)(k - 128) * DD + 2 * l);
        ldsw[i] = pack_bf16_pair(p[0], p[1]);
    }
    __syncthreads();
    int lane = t & 63, wave = t >> 6;
    int base = blockIdx.x * 64 + wave * 16;  // 16 output rows per wave
    float2 bv = ((const float2*)bias)[lane];
    for (int g = 0; g < 4; ++g) {
        int gb = base + g * 4;
        float2 as[4], an[4];
        int uu[4];
        #pragma unroll
        for (int r = 0; r < 4; ++r) {
            int u = users[gb + r];
            uu[r] = u;
            as[r] = ((const float2*)(h1 + (size_t)u * DD))[lane];
            int st = row_start[u];
            int dg = deg[u];
            int en = st + dg;
            float ax = 0.f, ay = 0.f;
            int e = st;
            for (; e + 4 <= en; e += 4) {
                int s0 = edge_src[e], s1 = edge_src[e + 1];
                int s2 = edge_src[e + 2], s3 = edge_src[e + 3];
                float2 v0 = ((const float2*)(h1 + (size_t)s0 * DD))[lane];
                float2 v1 = ((const float2*)(h1 + (size_t)s1 * DD))[lane];
                float2 v2 = ((const float2*)(h1 + (size_t)s2 * DD))[lane];
                float2 v3 = ((const float2*)(h1 + (size_t)s3 * DD))[lane];
                ax += v0.x + v1.x + v2.x + v3.x;
                ay += v0.y + v1.y + v2.y + v3.y;
            }
            for (; e < en; ++e) {
                int s = edge_src[e];
                float2 v = ((const float2*)(h1 + (size_t)s * DD))[lane];
                ax += v.x;
                ay += v.y;
            }
            float inv = 1.0f / fmaxf((float)dg, 1.0f);
            an[r] = make_float2(ax * inv, ay * inv);
        }
        float acc0[4], acc1[4];
        #pragma unroll
        for (int r = 0; r < 4; ++r) { acc0[r] = bv.x; acc1[r] = bv.y; }
        mat128_acc<4>(ldsw, lane, as, acc0, acc1);
        mat128_acc<4>(ldsw + 128 * 64, lane, an, acc0, acc1);
        #pragma unroll
        for (int r = 0; r < 4; ++r) {
            float2 o = leaky_l2(acc0[r], acc1[r]);
            float* orow = out + (size_t)(gb + r) * 384;
            ((float2*)orow)[lane] = ((const float2*)(ufeat + (size_t)uu[r] * DD))[lane];
            ((float2*)orow)[64 + lane] = as[r];
            ((float2*)orow)[128 + lane] = o;
        }
    }
}

// ---------- item side: only selected rows, 2 layers fused ----------
__global__ __launch_bounds__(256) void item_kernel(const float* __restrict__ ifeat,
                                                   const int* __restrict__ pos,
                                                   const int* __restrict__ neg,
                                                   const float* __restrict__ W0,
                                                   const float* __restrict__ b0,
                                                   const float* __restrict__ W1,
                                                   const float* __restrict__ b1,
                                                   float* __restrict__ out) {
    __shared__ unsigned ldsw[2 * 128 * 64];  // W0 then W1, 64 KB
    int t = threadIdx.x;
    for (int i = t; i < 128 * 64; i += 256) {
        int k = i >> 6, l = i & 63;
        ldsw[i] = pack_bf16_pair(W0[(size_t)k * DD + 2 * l], W0[(size_t)k * DD + 2 * l + 1]);
        ldsw[128 * 64 + i] =
            pack_bf16_pair(W1[(size_t)k * DD + 2 * l], W1[(size_t)k * DD + 2 * l + 1]);
    }
    __syncthreads();
    int lane = t & 63, wave = t >> 6;
    int base = blockIdx.x * 64 + wave * 16;  // 16 rows per wave; 512 blocks for 2*BB rows
    float2 b0v = ((const float2*)b0)[lane];
    float2 b1v = ((const float2*)b1)[lane];
    for (int g = 0; g < 4; ++g) {
        int gb = base + g * 4;
        float2 r0[4];
        #pragma unroll
        for (int r = 0; r < 4; ++r) {
            int b = gb + r;
            int it = (b < BB) ? pos[b] : neg[b - BB];
            r0[r] = ((const float2*)(ifeat + (size_t)it * DD))[lane];
        }
        float acc0[4], acc1[4];
        #pragma unroll
        for (int r = 0; r < 4; ++r) { acc0[r] = b0v.x; acc1[r] = b0v.y; }
        mat128_acc<4>(ldsw, lane, r0, acc0, acc1);
        float2 r1[4];
        #pragma unroll
        for (int r = 0; r < 4; ++r) r1[r] = leaky_l2(acc0[r], acc1[r]);
        #pragma unroll
        for (int r = 0; r < 4; ++r) { acc0[r] = b1v.x; acc1[r] = b1v.y; }
        mat128_acc<4>(ldsw + 128 * 64, lane, r1, acc0, acc1);
        #pragma unroll
        for (int r = 0; r < 4; ++r) {
            float2 r2 = leaky_l2(acc0[r], acc1[r]);
            int b = gb + r;
            size_t obase = (b < BB) ? ((size_t)BB * 384 + (size_t)b * 384)
                                    : ((size_t)2 * BB * 384 + (size_t)(b - BB) * 384);
            float* orow = out + obase;
            ((float2*)orow)[lane] = r0[r];
            ((float2*)orow)[64 + lane] = r1[r];
            ((float2*)orow)[128 + lane] = r2;
        }
    }
}

extern "C" void kernel_launch(void* const* d_in, const int* in_sizes, int n_in,
                              void* d_out, int out_size, void* d_ws, size_t ws_size,
                              hipStream_t stream) {
    const int* src = (const int*)d_in[0];
    const int* dst = (const int*)d_in[1];
    const int* users = (const int*)d_in[2];
    const int* pos = (const int*)d_in[3];
    const int* neg = (const int*)d_in[4];
    const float* ufeat = (const float*)d_in[5];
    const float* ifeat = (const float*)d_in[6];
    const float* Ws0 = (const float*)d_in[7];
    const float* Wn0 = (const float*)d_in[8];
    const float* bu0 = (const float*)d_in[9];
    const float* Wi0 = (const float*)d_in[10];
    const float* bi0 = (const float*)d_in[11];
    const float* Ws1 = (const float*)d_in[12];
    const float* Wn1 = (const float*)d_in[13];
    const float* bu1 = (const float*)d_in[14];
    const float* Wi1 = (const float*)d_in[15];
    const float* bi1 = (const float*)d_in[16];
    float* out = (float*)d_out;

    char* ws = (char*)d_ws;
    int* deg = (int*)(ws + OFF_DEG);
    int* row_start = (int*)(ws + OFF_ROWSTART);
    int* cursor = (int*)(ws + OFF_CURSOR);
    int* bsum = (int*)(ws + OFF_BSUM);
    int* edge_src = (int*)(ws + OFF_EDGESRC);
    float* h1 = (float*)(ws + OFF_H1);
    // neighbor-mean buffer lives in d_out (51.2 MB <= 75.5 MB); dead before
    // any real output is written (user_l2/item run after user_mm consumed it).
    float* hn = out;

    hipMemsetAsync(deg, 0, NU * sizeof(int), stream);
    deg_count_kernel<<<(NE + 255) / 256, 256, 0, stream>>>(dst, deg);
    scan1_kernel<<<SCAN_NBLK, 256, 0, stream>>>(deg, bsum);
    scan2_kernel<<<1, 64, 0, stream>>>(bsum);
    scan3_kernel<<<SCAN_NBLK, 256, 0, stream>>>(deg, bsum, row_start, cursor);
    fill_kernel<<<(NE + 255) / 256, 256, 0, stream>>>(src, dst, cursor, edge_src);
    agg_kernel<<<(NU + 3) / 4, 256, 0, stream>>>(ufeat, row_start, deg, edge_src, hn);
    user_mm_kernel<<<(NU + 63) / 64, 256, 0, stream>>>(ufeat, hn, Ws0, Wn0, bu0, h1);
    user_l2_kernel<<<BB / 64, 256, 0, stream>>>(ufeat, h1, users, row_start, deg, edge_src,
                                                Ws1, Wn1, bu1, out);
    item_kernel<<<(2 * BB) / 64, 256, 0, stream>>>(ifeat, pos, neg, Wi0, bi0, Wi1, bi1, out);
}

// Round 3
// 609.927 us; speedup vs baseline: 4.3297x; 1.5348x over previous
//
#include <hip/hip_runtime.h>

#define NU 100000
#define NI 100000
#define NE 1600000
#define BB 16384
#define DD 128

static constexpr int SCAN_CHUNK = 2048;                       // 256 threads * 8
static constexpr int SCAN_NBLK  = (NU + SCAN_CHUNK - 1) / SCAN_CHUNK; // 49
static constexpr int USER_TILES = NU / 16;                    // 6250

// ---------- workspace layout (bytes) ----------
static constexpr size_t OFF_DEG      = 0;          // int[NU]   400000
static constexpr size_t OFF_ROWSTART = 400128;     // int[NU]
static constexpr size_t OFF_CURSOR   = 800256;     // int[NU]
static constexpr size_t OFF_BSUM     = 1200384;    // int[64]
static constexpr size_t OFF_EDGESRC  = 1200640;    // int[NE]   6400000
static constexpr size_t OFF_H1       = 7600640;    // float[NU*DD] 51200000
static constexpr size_t OFF_WFRAG    = 58800640;   // u32x4[12288] 196608 (pre-swizzled bf16 weights)
// end = 58,997,248 bytes

// d_out staging (dead before real outputs are written):
//   ubf   at d_out+0        : uint[NU*64]  25.6 MB  (ufeat in bf16 pairs)
//   hn_bf at d_out+25.6MB   : ushort[NU*128] 25.6 MB (neighbor mean, bf16)
// user_l2 writes rows 0..BB-1 (bytes 0..25.2M, ubf dead by then);
// item writes rows BB..3BB-1 (overlaps hn_bf region, dead by then).

typedef __bf16 bf16x8 __attribute__((ext_vector_type(8)));
typedef float f32x4 __attribute__((ext_vector_type(4)));
typedef unsigned int u32x4 __attribute__((ext_vector_type(4)));

union frag_u {
    u32x4 u;
    bf16x8 b;
    unsigned short us[8];
};

// ---------- helpers ----------
__device__ __forceinline__ unsigned short f2bf(float f) {
    unsigned u = __float_as_uint(f);
    u = (u + 0x7fffu + ((u >> 16) & 1u)) >> 16;  // RNE
    return (unsigned short)u;
}

__device__ __forceinline__ unsigned pack_bf16_pair(float a, float b) {
    return (unsigned)f2bf(a) | ((unsigned)f2bf(b) << 16);
}

__device__ __forceinline__ float2 unpack_bf16_pair(unsigned u) {
    float2 r;
    r.x = __uint_as_float(u << 16);
    r.y = __uint_as_float(u & 0xffff0000u);
    return r;
}

__device__ __forceinline__ f32x4 mfma16(bf16x8 a, bf16x8 b, f32x4 c) {
    return __builtin_amdgcn_mfma_f32_16x16x32_bf16(a, b, c, 0, 0, 0);
}

__device__ __forceinline__ bf16x8 bfrag(const u32x4* __restrict__ wf, int idx) {
    frag_u f;
    f.u = wf[idx];
    return f.b;
}

// A-fragment (16x16x32 layout: lane holds A[m=lane&15][kb..kb+7]) as hi/lo bf16 split.
__device__ __forceinline__ void make_afrag_hilo(const float* rowp, int kb,
                                                bf16x8* hi, bf16x8* lo) {
    float4 v0 = *(const float4*)(rowp + kb);
    float4 v1 = *(const float4*)(rowp + kb + 4);
    float vv[8] = {v0.x, v0.y, v0.z, v0.w, v1.x, v1.y, v1.z, v1.w};
    frag_u h, l;
    #pragma unroll
    for (int e = 0; e < 8; ++e) {
        unsigned short hb = f2bf(vv[e]);
        h.us[e] = hb;
        float hf = __uint_as_float(((unsigned)hb) << 16);
        l.us[e] = f2bf(vv[e] - hf);
    }
    *hi = h.b;
    *lo = l.b;
}

// ---------- CSR build ----------
__global__ __launch_bounds__(256) void deg_count_kernel(const int* __restrict__ dst,
                                                        int* __restrict__ deg) {
    int i = blockIdx.x * blockDim.x + threadIdx.x;
    int stride = gridDim.x * blockDim.x;
    for (; i < NE; i += stride) atomicAdd(&deg[dst[i]], 1);
}

__global__ __launch_bounds__(256) void scan1_kernel(const int* __restrict__ deg,
                                                    int* __restrict__ bsum) {
    __shared__ int sh[256];
    int t = threadIdx.x;
    int base = blockIdx.x * SCAN_CHUNK + t * 8;
    int s = 0;
    #pragma unroll
    for (int j = 0; j < 8; ++j) {
        int idx = base + j;
        s += (idx < NU) ? deg[idx] : 0;
    }
    sh[t] = s;
    __syncthreads();
    for (int off = 128; off > 0; off >>= 1) {
        if (t < off) sh[t] += sh[t + off];
        __syncthreads();
    }
    if (t == 0) bsum[blockIdx.x] = sh[0];
}

__global__ void scan2_kernel(int* __restrict__ bsum) {
    if (threadIdx.x == 0) {
        int acc = 0;
        for (int i = 0; i < SCAN_NBLK; ++i) {
            int v = bsum[i];
            bsum[i] = acc;
            acc += v;
        }
    }
}

__global__ __launch_bounds__(256) void scan3_kernel(const int* __restrict__ deg,
                                                    const int* __restrict__ bsum,
                                                    int* __restrict__ row_start,
                                                    int* __restrict__ cursor) {
    __shared__ int sh[256];
    int t = threadIdx.x;
    int base = blockIdx.x * SCAN_CHUNK + t * 8;
    int v[8];
    int s = 0;
    #pragma unroll
    for (int j = 0; j < 8; ++j) {
        int idx = base + j;
        v[j] = (idx < NU) ? deg[idx] : 0;
        s += v[j];
    }
    sh[t] = s;
    __syncthreads();
    for (int off = 1; off < 256; off <<= 1) {
        int val = sh[t];
        int add = (t >= off) ? sh[t - off] : 0;
        __syncthreads();
        sh[t] = val + add;
        __syncthreads();
    }
    int excl = sh[t] - s + bsum[blockIdx.x];
    #pragma unroll
    for (int j = 0; j < 8; ++j) {
        int idx = base + j;
        if (idx < NU) {
            row_start[idx] = excl;
            cursor[idx] = excl;
        }
        excl += v[j];
    }
}

__global__ __launch_bounds__(256) void fill_kernel(const int* __restrict__ src,
                                                   const int* __restrict__ dst,
                                                   int* __restrict__ cursor,
                                                   int* __restrict__ edge_src) {
    int i = blockIdx.x * blockDim.x + threadIdx.x;
    int stride = gridDim.x * blockDim.x;
    for (; i < NE; i += stride) {
        int d = dst[i];
        int p = atomicAdd(&cursor[d], 1);
        edge_src[p] = src[i];
    }
}

// ---------- weight pre-swizzle: global fp32 [k][n] -> bf16 B-fragments ----------
// entry idx = matg*2048 + (j*4+kk)*64 + lane ; holds B[kb..kb+7][n] with
// n = j*16 + (lane&15), kb = kk*32 + (lane>>4)*8. 6 matrices, 12288 entries.
__global__ __launch_bounds__(256) void pack_swizzle_kernel(
    const float* __restrict__ Ws0, const float* __restrict__ Wn0,
    const float* __restrict__ Ws1, const float* __restrict__ Wn1,
    const float* __restrict__ Wi0, const float* __restrict__ Wi1,
    u32x4* __restrict__ wfrag) {
    int i = blockIdx.x * 256 + threadIdx.x;  // grid 48 -> 12288
    const float* tab[6] = {Ws0, Wn0, Ws1, Wn1, Wi0, Wi1};
    int matg = i >> 11;
    int j = (i >> 8) & 7, kk = (i >> 6) & 3, ln = i & 63;
    const float* W = tab[matg];
    int n = j * 16 + (ln & 15);
    int kb = kk * 32 + (ln >> 4) * 8;
    unsigned short u[8];
    #pragma unroll
    for (int e = 0; e < 8; ++e) u[e] = f2bf(W[(size_t)(kb + e) * DD + n]);
    u32x4 w;
    w[0] = u[0] | ((unsigned)u[1] << 16);
    w[1] = u[2] | ((unsigned)u[3] << 16);
    w[2] = u[4] | ((unsigned)u[5] << 16);
    w[3] = u[6] | ((unsigned)u[7] << 16);
    wfrag[i] = w;
}

// ---------- ufeat fp32 -> packed bf16 pairs ----------
__global__ __launch_bounds__(256) void cvt_kernel(const float* __restrict__ uf,
                                                  unsigned* __restrict__ ubf) {
    int i = blockIdx.x * 256 + threadIdx.x;  // grid 25000 -> NU*64 exact
    float2 v = ((const float2*)uf)[i];
    ubf[i] = pack_bf16_pair(v.x, v.y);
}

// ---------- layer-1 aggregation (bf16 gather, bf16 mean out) ----------
__global__ __launch_bounds__(256) void agg_kernel(const unsigned* __restrict__ ubf,
                                                  const int* __restrict__ row_start,
                                                  const int* __restrict__ deg,
                                                  const int* __restrict__ edge_src,
                                                  unsigned* __restrict__ hn) {
    int wid = blockIdx.x * 4 + (threadIdx.x >> 6);
    int lane = threadIdx.x & 63;
    if (wid >= NU) return;
    int st = row_start[wid];
    int dg = deg[wid];
    int en = st + dg;
    float ax = 0.f, ay = 0.f;
    int e = st;
    for (; e + 4 <= en; e += 4) {
        int s0 = edge_src[e], s1 = edge_src[e + 1], s2 = edge_src[e + 2], s3 = edge_src[e + 3];
        float2 v0 = unpack_bf16_pair(ubf[(size_t)s0 * 64 + lane]);
        float2 v1 = unpack_bf16_pair(ubf[(size_t)s1 * 64 + lane]);
        float2 v2 = unpack_bf16_pair(ubf[(size_t)s2 * 64 + lane]);
        float2 v3 = unpack_bf16_pair(ubf[(size_t)s3 * 64 + lane]);
        ax += v0.x + v1.x + v2.x + v3.x;
        ay += v0.y + v1.y + v2.y + v3.y;
    }
    for (; e < en; ++e) {
        float2 v = unpack_bf16_pair(ubf[(size_t)edge_src[e] * 64 + lane]);
        ax += v.x;
        ay += v.y;
    }
    float inv = 1.0f / fmaxf((float)dg, 1.0f);
    hn[(size_t)wid * 64 + lane] = pack_bf16_pair(ax * inv, ay * inv);
}

// ---------- user layer 1 (all rows), MFMA ----------
__global__ __launch_bounds__(256) void user_mm_mfma(
    const float* __restrict__ hself, const unsigned short* __restrict__ hn,
    const u32x4* __restrict__ wf, const float* __restrict__ bias,
    float* __restrict__ out) {
    int t = threadIdx.x;
    int lane = t & 63;
    int tile = blockIdx.x * 4 + (t >> 6);
    if (tile >= USER_TILES) return;
    int gbase = tile * 16;
    int m = lane & 15, q = lane >> 4;
    const float* selfp = hself + (size_t)(gbase + m) * DD;
    const unsigned short* neighp = hn + (size_t)(gbase + m) * DD;
    bf16x8 as_hi[4], as_lo[4], an[4];
    #pragma unroll
    for (int kk = 0; kk < 4; ++kk) {
        int kb = kk * 32 + q * 8;
        make_afrag_hilo(selfp, kb, &as_hi[kk], &as_lo[kk]);
        frag_u f;
        f.u = *(const u32x4*)(neighp + kb);  // hn already bf16: hi only
        an[kk] = f.b;
    }
    f32x4 acc[8];
    f32x4 zero = {0.f, 0.f, 0.f, 0.f};
    #pragma unroll
    for (int j = 0; j < 8; ++j) acc[j] = zero;
    #pragma unroll 2
    for (int j = 0; j < 8; ++j) {
        #pragma unroll
        for (int kk = 0; kk < 4; ++kk) {
            bf16x8 bs = bfrag(wf, (j * 4 + kk) * 64 + lane);
            acc[j] = mfma16(as_hi[kk], bs, acc[j]);
            acc[j] = mfma16(as_lo[kk], bs, acc[j]);
            bf16x8 bn = bfrag(wf, 2048 + (j * 4 + kk) * 64 + lane);
            acc[j] = mfma16(an[kk], bn, acc[j]);
        }
    }
    float ss[4] = {0.f, 0.f, 0.f, 0.f};
    #pragma unroll
    for (int j = 0; j < 8; ++j) {
        float bj = bias[j * 16 + m];
        #pragma unroll
        for (int r = 0; r < 4; ++r) {
            float x = acc[j][r] + bj;
            x = x > 0.f ? x : 0.2f * x;
            acc[j][r] = x;
            ss[r] += x * x;
        }
    }
    #pragma unroll
    for (int r = 0; r < 4; ++r) {
        float s = ss[r];
        s += __shfl_xor(s, 1, 64);
        s += __shfl_xor(s, 2, 64);
        s += __shfl_xor(s, 4, 64);
        s += __shfl_xor(s, 8, 64);
        ss[r] = 1.0f / fmaxf(sqrtf(s), 1e-12f);
    }
    #pragma unroll
    for (int j = 0; j < 8; ++j)
        #pragma unroll
        for (int r = 0; r < 4; ++r)
            out[(size_t)(gbase + q * 4 + r) * DD + j * 16 + m] = acc[j][r] * ss[r];
}

// ---------- user layer 2 (users rows): fused agg + MFMA + output ----------
__global__ __launch_bounds__(256) void user_l2_mfma(
    const float* __restrict__ ufeat, const float* __restrict__ h1,
    const int* __restrict__ users, const int* __restrict__ row_start,
    const int* __restrict__ deg, const int* __restrict__ edge_src,
    const u32x4* __restrict__ wf, const float* __restrict__ bias,
    float* __restrict__ out) {
    __shared__ float scratch[4][16 * 132];  // per-wave, stride 132 (16B-aligned rows)
    int t = threadIdx.x;
    int lane = t & 63, wave = t >> 6;
    int tile = blockIdx.x * 4 + wave;  // 1024 tiles exact
    int gb = tile * 16;
    float* sc = scratch[wave];
    // phase 1: per-row wave aggregation of h1 into scratch + copy cols 0..255
    for (int r = 0; r < 16; ++r) {
        int u = users[gb + r];
        int st = row_start[u], dg = deg[u], en = st + dg;
        float ax = 0.f, ay = 0.f;
        int e = st;
        for (; e + 4 <= en; e += 4) {
            int s0 = edge_src[e], s1 = edge_src[e + 1];
            int s2 = edge_src[e + 2], s3 = edge_src[e + 3];
            float2 v0 = ((const float2*)(h1 + (size_t)s0 * DD))[lane];
            float2 v1 = ((const float2*)(h1 + (size_t)s1 * DD))[lane];
            float2 v2 = ((const float2*)(h1 + (size_t)s2 * DD))[lane];
            float2 v3 = ((const float2*)(h1 + (size_t)s3 * DD))[lane];
            ax += v0.x + v1.x + v2.x + v3.x;
            ay += v0.y + v1.y + v2.y + v3.y;
        }
        for (; e < en; ++e) {
            float2 v = ((const float2*)(h1 + (size_t)edge_src[e] * DD))[lane];
            ax += v.x;
            ay += v.y;
        }
        float inv = 1.0f / fmaxf((float)dg, 1.0f);
        sc[r * 132 + 2 * lane] = ax * inv;
        sc[r * 132 + 2 * lane + 1] = ay * inv;
        float* orow = out + (size_t)(gb + r) * 384;
        ((float2*)orow)[lane] = ((const float2*)(ufeat + (size_t)u * DD))[lane];
        ((float2*)orow)[64 + lane] = ((const float2*)(h1 + (size_t)u * DD))[lane];
    }
    // phase 2: MFMA
    int m = lane & 15, q = lane >> 4;
    int um = users[gb + m];
    const float* selfp = h1 + (size_t)um * DD;
    bf16x8 sh[4], sl[4], nh[4], nl[4];
    #pragma unroll
    for (int kk = 0; kk < 4; ++kk) {
        int kb = kk * 32 + q * 8;
        make_afrag_hilo(selfp, kb, &sh[kk], &sl[kk]);
        make_afrag_hilo(sc + m * 132, kb, &nh[kk], &nl[kk]);
    }
    f32x4 acc[8];
    f32x4 zero = {0.f, 0.f, 0.f, 0.f};
    #pragma unroll
    for (int j = 0; j < 8; ++j) acc[j] = zero;
    #pragma unroll 2
    for (int j = 0; j < 8; ++j) {
        #pragma unroll
        for (int kk = 0; kk < 4; ++kk) {
            bf16x8 bs = bfrag(wf, (j * 4 + kk) * 64 + lane);
            acc[j] = mfma16(sh[kk], bs, acc[j]);
            acc[j] = mfma16(sl[kk], bs, acc[j]);
            bf16x8 bn = bfrag(wf, 2048 + (j * 4 + kk) * 64 + lane);
            acc[j] = mfma16(nh[kk], bn, acc[j]);
            acc[j] = mfma16(nl[kk], bn, acc[j]);
        }
    }
    float ss[4] = {0.f, 0.f, 0.f, 0.f};
    #pragma unroll
    for (int j = 0; j < 8; ++j) {
        float bj = bias[j * 16 + m];
        #pragma unroll
        for (int r = 0; r < 4; ++r) {
            float x = acc[j][r] + bj;
            x = x > 0.f ? x : 0.2f * x;
            acc[j][r] = x;
            ss[r] += x * x;
        }
    }
    #pragma unroll
    for (int r = 0; r < 4; ++r) {
        float s = ss[r];
        s += __shfl_xor(s, 1, 64);
        s += __shfl_xor(s, 2, 64);
        s += __shfl_xor(s, 4, 64);
        s += __shfl_xor(s, 8, 64);
        ss[r] = 1.0f / fmaxf(sqrtf(s), 1e-12f);
    }
    #pragma unroll
    for (int j = 0; j < 8; ++j)
        #pragma unroll
        for (int r = 0; r < 4; ++r)
            out[(size_t)(gb + q * 4 + r) * 384 + 256 + j * 16 + m] = acc[j][r] * ss[r];
}

// ---------- item side (pos|neg rows), 2 layers, MFMA ----------
__global__ __launch_bounds__(256) void item_mfma(
    const float* __restrict__ ifeat, const int* __restrict__ pos,
    const int* __restrict__ neg, const u32x4* __restrict__ wf,
    const float* __restrict__ b0, const float* __restrict__ b1,
    float* __restrict__ out) {
    __shared__ float scratch[4][16 * 132];
    int t = threadIdx.x;
    int lane = t & 63, wave = t >> 6;
    int tile = blockIdx.x * 4 + wave;  // 2048 tiles exact
    int gb = tile * 16;
    int m = lane & 15, q = lane >> 4;
    float* sc = scratch[wave];
    int rowm = gb + m;
    int idxm = (rowm < BB) ? pos[rowm] : neg[rowm - BB];
    const float* rowp = ifeat + (size_t)idxm * DD;
    bf16x8 ahi[4], alo[4];
    #pragma unroll
    for (int kk = 0; kk < 4; ++kk)
        make_afrag_hilo(rowp, kk * 32 + q * 8, &ahi[kk], &alo[kk]);
    f32x4 acc[8];
    f32x4 zero = {0.f, 0.f, 0.f, 0.f};
    #pragma unroll
    for (int j = 0; j < 8; ++j) acc[j] = zero;
    #pragma unroll 2
    for (int j = 0; j < 8; ++j) {
        #pragma unroll
        for (int kk = 0; kk < 4; ++kk) {
            bf16x8 b = bfrag(wf, (j * 4 + kk) * 64 + lane);
            acc[j] = mfma16(ahi[kk], b, acc[j]);
            acc[j] = mfma16(alo[kk], b, acc[j]);
        }
    }
    // epilogue 0 -> r1 in scratch
    float ss[4] = {0.f, 0.f, 0.f, 0.f};
    #pragma unroll
    for (int j = 0; j < 8; ++j) {
        float bj = b0[j * 16 + m];
        #pragma unroll
        for (int r = 0; r < 4; ++r) {
            float x = acc[j][r] + bj;
            x = x > 0.f ? x : 0.2f * x;
            acc[j][r] = x;
            ss[r] += x * x;
        }
    }
    #pragma unroll
    for (int r = 0; r < 4; ++r) {
        float s = ss[r];
        s += __shfl_xor(s, 1, 64);
        s += __shfl_xor(s, 2, 64);
        s += __shfl_xor(s, 4, 64);
        s += __shfl_xor(s, 8, 64);
        ss[r] = 1.0f / fmaxf(sqrtf(s), 1e-12f);
    }
    #pragma unroll
    for (int j = 0; j < 8; ++j)
        #pragma unroll
        for (int r = 0; r < 4; ++r)
            sc[(q * 4 + r) * 132 + j * 16 + m] = acc[j][r] * ss[r];
    // copy r0 (raw gathered ifeat) and r1 (from scratch) to output
    for (int r = 0; r < 16; ++r) {
        int row = gb + r;
        int idx = (row < BB) ? pos[row] : neg[row - BB];
        float* orow = out + (size_t)(BB + row) * 384;  // pos b -> BB+b, neg b' -> 2BB+b' == BB+row
        ((float2*)orow)[lane] = ((const float2*)(ifeat + (size_t)idx * DD))[lane];
        float2 r1v;
        r1v.x = sc[r * 132 + 2 * lane];
        r1v.y = sc[r * 132 + 2 * lane + 1];
        ((float2*)orow)[64 + lane] = r1v;
    }
    // layer 1: A-frags from scratch
    bf16x8 chi[4], clo[4];
    #pragma unroll
    for (int kk = 0; kk < 4; ++kk)
        make_afrag_hilo(sc + m * 132, kk * 32 + q * 8, &chi[kk], &clo[kk]);
    #pragma unroll
    for (int j = 0; j < 8; ++j) acc[j] = zero;
    #pragma unroll 2
    for (int j = 0; j < 8; ++j) {
        #pragma unroll
        for (int kk = 0; kk < 4; ++kk) {
            bf16x8 b = bfrag(wf, 2048 + (j * 4 + kk) * 64 + lane);
            acc[j] = mfma16(chi[kk], b, acc[j]);
            acc[j] = mfma16(clo[kk], b, acc[j]);
        }
    }
    float ss1[4] = {0.f, 0.f, 0.f, 0.f};
    #pragma unroll
    for (int j = 0; j < 8; ++j) {
        float bj = b1[j * 16 + m];
        #pragma unroll
        for (int r = 0; r < 4; ++r) {
            float x = acc[j][r] + bj;
            x = x > 0.f ? x : 0.2f * x;
            acc[j][r] = x;
            ss1[r] += x * x;
        }
    }
    #pragma unroll
    for (int r = 0; r < 4; ++r) {
        float s = ss1[r];
        s += __shfl_xor(s, 1, 64);
        s += __shfl_xor(s, 2, 64);
        s += __shfl_xor(s, 4, 64);
        s += __shfl_xor(s, 8, 64);
        ss1[r] = 1.0f / fmaxf(sqrtf(s), 1e-12f);
    }
    #pragma unroll
    for (int j = 0; j < 8; ++j)
        #pragma unroll
        for (int r = 0; r < 4; ++r)
            out[(size_t)(BB + gb + q * 4 + r) * 384 + 256 + j * 16 + m] = acc[j][r] * ss1[r];
}

extern "C" void kernel_launch(void* const* d_in, const int* in_sizes, int n_in,
                              void* d_out, int out_size, void* d_ws, size_t ws_size,
                              hipStream_t stream) {
    const int* src = (const int*)d_in[0];
    const int* dst = (const int*)d_in[1];
    const int* users = (const int*)d_in[2];
    const int* pos = (const int*)d_in[3];
    const int* neg = (const int*)d_in[4];
    const float* ufeat = (const float*)d_in[5];
    const float* ifeat = (const float*)d_in[6];
    const float* Ws0 = (const float*)d_in[7];
    const float* Wn0 = (const float*)d_in[8];
    const float* bu0 = (const float*)d_in[9];
    const float* Wi0 = (const float*)d_in[10];
    const float* bi0 = (const float*)d_in[11];
    const float* Ws1 = (const float*)d_in[12];
    const float* Wn1 = (const float*)d_in[13];
    const float* bu1 = (const float*)d_in[14];
    const float* Wi1 = (const float*)d_in[15];
    const float* bi1 = (const float*)d_in[16];
    float* out = (float*)d_out;

    char* ws = (char*)d_ws;
    int* deg = (int*)(ws + OFF_DEG);
    int* row_start = (int*)(ws + OFF_ROWSTART);
    int* cursor = (int*)(ws + OFF_CURSOR);
    int* bsum = (int*)(ws + OFF_BSUM);
    int* edge_src = (int*)(ws + OFF_EDGESRC);
    float* h1 = (float*)(ws + OFF_H1);
    u32x4* wfrag = (u32x4*)(ws + OFF_WFRAG);

    unsigned* ubf = (unsigned*)d_out;                                    // bf16 ufeat
    unsigned* hn = (unsigned*)((char*)d_out + (size_t)NU * DD * 2);      // bf16 neighbor mean
    const unsigned short* hn_us = (const unsigned short*)hn;

    hipMemsetAsync(deg, 0, NU * sizeof(int), stream);
    pack_swizzle_kernel<<<48, 256, 0, stream>>>(Ws0, Wn0, Ws1, Wn1, Wi0, Wi1, wfrag);
    deg_count_kernel<<<(NE + 255) / 256, 256, 0, stream>>>(dst, deg);
    scan1_kernel<<<SCAN_NBLK, 256, 0, stream>>>(deg, bsum);
    scan2_kernel<<<1, 64, 0, stream>>>(bsum);
    scan3_kernel<<<SCAN_NBLK, 256, 0, stream>>>(deg, bsum, row_start, cursor);
    fill_kernel<<<(NE + 255) / 256, 256, 0, stream>>>(src, dst, cursor, edge_src);
    cvt_kernel<<<NU * 64 / 256, 256, 0, stream>>>(ufeat, ubf);
    agg_kernel<<<(NU + 3) / 4, 256, 0, stream>>>(ubf, row_start, deg, edge_src, hn);
    user_mm_mfma<<<(USER_TILES + 3) / 4, 256, 0, stream>>>(ufeat, hn_us, wfrag, bu0, h1);
    user_l2_mfma<<<BB / 64, 256, 0, stream>>>(ufeat, h1, users, row_start, deg, edge_src,
                                              wfrag + 4096, bu1, out);
    item_mfma<<<2 * BB / 64, 256, 0, stream>>>(ifeat, pos, neg, wfrag + 8192, bi0, bi1, out);
}